// Round 9
// baseline (203.255 us; speedup 1.0000x reference)
//
#include <hip/hip_runtime.h>

// Problem constants: N=20000, T=4, F_IN=F_OUT=64, E=640000
#define N_NODES 20000
#define T_STEPS 4
#define F_DIM   64
#define E_EDGES 640000
#define ROWS    (N_NODES * T_STEPS)   // 80000
#define ROW_ELEMS (T_STEPS * F_DIM)   // 256 elems per node row

#define RB       64                   // dst nodes per range
#define NRANGE   313                  // ceil(20000/64)
#define CAPF     3072                 // record cap per range (lambda ~2048, +22 sigma)
#define PART_BLOCKS   128
#define EDGES_PER_PB  5000            // 128 * 5000 = 640000
#define ROUND_E  250
#define NROUNDS  20                   // 20 * 250 = 5000
#define STAGE_D  8                    // staged records per bucket (2 lines)
#define TRANSFORM_BLOCKS (ROWS / 64)  // 1250
#define OVF_CAP  4096

__device__ __forceinline__ unsigned short f32_to_bf16_rne(float f) {
    unsigned u = __float_as_uint(f);
    u += 0x7FFFu + ((u >> 16) & 1u);
    return (unsigned short)(u >> 16);
}
__device__ __forceinline__ float bf16_to_f32(unsigned short h) {
    return __uint_as_float((unsigned)h << 16);
}
// 12-bit fixed-point weight in [0,1): abs err <= 2^-13 (better than bf16).
__device__ __forceinline__ unsigned w_to_u12(float f) {
    unsigned q = __float2uint_rn(f * 4096.0f);
    return q > 4095u ? 4095u : q;
}

// ---------------------------------------------------------------------------
// R8 post-mortem: removing ALL global atomics left the scatter at 51.6us ->
// atomics were never the wall. Ledger: payload x, bytes x, occupancy x,
// TLP x, atomics x. The invariant is 640k random PARTIAL-LINE stores, each
// forcing an L2 write-allocate fetch (~300-400cy round trip to MALL); rec
// write traffic at 4.3x its region confirms per-store line dirtying.
// R9: make (almost) every scatter store a FULL 64B line.
//   K1: 128 partition blocks stage records in a 313-bucket x 8-slot LDS
//       cache; flush aligned 4-record (64B) groups per round (bases from
//       atomicAdd(+4k) stay 4-aligned -> complete lines, no fetch-on-write).
//       ~90% of records leave as full lines. + 1250 transform blocks.
//   K2: 313 per-range sort blocks -> dense per-node 8B CSR rows, in-place,
//       single-writer region. Replaces R8's hist/scan_a/scan_b.
//   K3: R8 accumulate (proven <50us) on range-local CSR + fused ovf fixup.
// ---------------------------------------------------------------------------
__global__ __launch_bounds__(256) void build_kernel(
    const float* __restrict__ x, const float* __restrict__ W,
    unsigned short* __restrict__ yb,
    const int* __restrict__ src, const int* __restrict__ dst,
    const float* __restrict__ ew,
    int* __restrict__ gcnt, int4* __restrict__ bktF,
    int4* __restrict__ ovf, int* __restrict__ ovf_cnt)
{
    __shared__ int4 stage[NRANGE * STAGE_D];   // 40064 B (transform overlays wt)
    __shared__ int  scnt[NRANGE];              // 1252 B

    const int tid = threadIdx.x;

    if (blockIdx.x < PART_BLOCKS) {
        for (int i = tid; i < NRANGE; i += 256) scnt[i] = 0;
        __syncthreads();
        const int base = blockIdx.x * EDGES_PER_PB;

        for (int rd = 0; rd < NROUNDS; ++rd) {
            if (tid < ROUND_E) {
                const int e = base + rd * ROUND_E + tid;
                const unsigned w0 = w_to_u12(ew[e]);
                const unsigned w1 = w_to_u12(ew[E_EDGES + e]);
                const unsigned w2 = w_to_u12(ew[2 * E_EDGES + e]);
                const unsigned w3 = w_to_u12(ew[3 * E_EDGES + e]);
                const unsigned s  = (unsigned)src[e];
                const int d = dst[e];
                int4 rec;
                rec.x = (int)(s | (w0 << 16) | (w1 << 28));
                rec.y = (int)((w1 >> 4) | (w2 << 8) | (w3 << 20));
                rec.z = d;
                rec.w = 0;
                const int r = d >> 6;
                const int p = atomicAdd(&scnt[r], 1);
                if (p < STAGE_D) {
                    stage[r * STAGE_D + p] = rec;
                } else {            // stage overflow: ~1e-4 of edges
                    const int o = atomicAdd(ovf_cnt, 1);
                    if (o < OVF_CAP) ovf[o] = rec;
                }
            }
            __syncthreads();
            // flush full 4-record (64B) groups; bases stay 4-aligned
            for (int r = tid; r < NRANGE; r += 256) {
                const int c  = scnt[r];
                const int st = c > STAGE_D ? STAGE_D : c;
                const int k  = st & ~3;
                if (k) {
                    const int bg = atomicAdd(&gcnt[r], k);
                    for (int q = 0; q < k; ++q) {
                        const int slot = bg + q;
                        const int4 rc = stage[r * STAGE_D + q];
                        if (slot < CAPF) bktF[(size_t)r * CAPF + slot] = rc;
                        else { const int o = atomicAdd(ovf_cnt, 1); if (o < OVF_CAP) ovf[o] = rc; }
                    }
                    for (int q = k; q < st; ++q)
                        stage[r * STAGE_D + (q - k)] = stage[r * STAGE_D + q];
                }
                scnt[r] = st - k;
            }
            __syncthreads();
        }
        // drain remainders (<4 records/bucket; the ~10% partial-line tail)
        for (int r = tid; r < NRANGE; r += 256) {
            const int st = scnt[r];
            if (st) {
                const int bg = atomicAdd(&gcnt[r], st);
                for (int q = 0; q < st; ++q) {
                    const int slot = bg + q;
                    const int4 rc = stage[r * STAGE_D + q];
                    if (slot < CAPF) bktF[(size_t)r * CAPF + slot] = rc;
                    else { const int o = atomicAdd(ovf_cnt, 1); if (o < OVF_CAP) ovf[o] = rc; }
                }
            }
        }
        return;
    }

    // ---- transform: y = x @ W^T (64x64 fp32) stored bf16 ----
    float* wt = (float*)stage;          // 16KB overlay of the 40KB stage
    const int row0 = (blockIdx.x - PART_BLOCKS) * 64;

    {
        const int o  = tid & 63;
        const int fb = (tid >> 6) * 16;
#pragma unroll
        for (int k = 0; k < 16; ++k) {
            const int f = fb + k;
            wt[f * 64 + o] = W[o * 64 + f];
        }
    }
    __syncthreads();

    const int rg = tid >> 4;          // 0..15: row group (4 rows)
    const int oq = (tid & 15) * 4;    // output quad

    float acc[4][4];
#pragma unroll
    for (int i = 0; i < 4; ++i)
#pragma unroll
        for (int j = 0; j < 4; ++j) acc[i][j] = 0.0f;

    const float4* xg4 = (const float4*)(x + (size_t)(row0 + rg * 4) * 64);

#pragma unroll 4
    for (int fc = 0; fc < 16; ++fc) {
        float4 xv[4];
#pragma unroll
        for (int i = 0; i < 4; ++i) xv[i] = xg4[i * 16 + fc];
#pragma unroll
        for (int j = 0; j < 4; ++j) {
            const int f = fc * 4 + j;
            const float4 w4 = *(const float4*)&wt[f * 64 + oq];
            const float xj0 = j == 0 ? xv[0].x : j == 1 ? xv[0].y : j == 2 ? xv[0].z : xv[0].w;
            const float xj1 = j == 0 ? xv[1].x : j == 1 ? xv[1].y : j == 2 ? xv[1].z : xv[1].w;
            const float xj2 = j == 0 ? xv[2].x : j == 1 ? xv[2].y : j == 2 ? xv[2].z : xv[2].w;
            const float xj3 = j == 0 ? xv[3].x : j == 1 ? xv[3].y : j == 2 ? xv[3].z : xv[3].w;
            acc[0][0] += xj0 * w4.x; acc[0][1] += xj0 * w4.y; acc[0][2] += xj0 * w4.z; acc[0][3] += xj0 * w4.w;
            acc[1][0] += xj1 * w4.x; acc[1][1] += xj1 * w4.y; acc[1][2] += xj1 * w4.z; acc[1][3] += xj1 * w4.w;
            acc[2][0] += xj2 * w4.x; acc[2][1] += xj2 * w4.y; acc[2][2] += xj2 * w4.z; acc[2][3] += xj2 * w4.w;
            acc[3][0] += xj3 * w4.x; acc[3][1] += xj3 * w4.y; acc[3][2] += xj3 * w4.z; acc[3][3] += xj3 * w4.w;
        }
    }

#pragma unroll
    for (int i = 0; i < 4; ++i) {
        const int r = row0 + rg * 4 + i;
        ushort4 h;
        h.x = f32_to_bf16_rne(acc[i][0]);
        h.y = f32_to_bf16_rne(acc[i][1]);
        h.z = f32_to_bf16_rne(acc[i][2]);
        h.w = f32_to_bf16_rne(acc[i][3]);
        *(ushort4*)(yb + (size_t)r * 64 + oq) = h;
    }
}

// ---------------------------------------------------------------------------
// K2: per-range sort. Block r loads its bucket (<=3072 x 16B) to LDS,
// 64-bin histogram + prefix, writes dense 8B records back IN PLACE (reads
// all done before first write; only block r touches row r) and packed
// nodeinfo[n] = off | deg<<16.
// ---------------------------------------------------------------------------
__global__ __launch_bounds__(256) void sort_kernel(
    const int* __restrict__ gcnt, int4* __restrict__ bktF,
    unsigned int* __restrict__ nodeinfo)
{
    __shared__ int4 lrec[CAPF];          // 48 KB
    __shared__ int hist[RB], pstart[RB], cnt2[RB];
    const int tid = threadIdx.x;
    const int r   = blockIdx.x;

    int m = gcnt[r]; if (m > CAPF) m = CAPF;
    int4* rowp = bktF + (size_t)r * CAPF;

    for (int i = tid; i < m; i += 256) lrec[i] = rowp[i];
    if (tid < RB) { hist[tid] = 0; cnt2[tid] = 0; }
    __syncthreads();

    for (int i = tid; i < m; i += 256) atomicAdd(&hist[lrec[i].z & 63], 1);
    __syncthreads();

    if (tid == 0) {
        int run = 0;
        for (int i = 0; i < RB; ++i) { pstart[i] = run; run += hist[i]; }
    }
    __syncthreads();

    if (tid < RB)
        nodeinfo[r * RB + tid] = (unsigned)pstart[tid] | ((unsigned)hist[tid] << 16);

    uint2* out8 = (uint2*)rowp;          // in-place: first 24KB of the row
    for (int i = tid; i < m; i += 256) {
        const int4 rc = lrec[i];
        const int d6  = rc.z & 63;
        const int rank = atomicAdd(&cnt2[d6], 1);
        out8[pstart[d6] + rank] = make_uint2((unsigned)rc.x, (unsigned)rc.y);
    }
}

// Per-lane weight decode: t = lane>>4 selects w_t, shift = 16 + 12*t.
__device__ __forceinline__ float dec_w(uint2 r, int t) {
    const unsigned long long pk = (unsigned long long)r.x |
                                  ((unsigned long long)r.y << 32);
    const unsigned q = (unsigned)(pk >> (16 + 12 * t)) & 0xFFFu;
    return (float)q * (1.0f / 4096.0f);
}

// 4-record batch: all register indices compile-time (rule #20).
#define BATCH4(RP, K0)                                                        \
    {                                                                         \
        const uint2 R0 = (RP)[(K0) + 0], R1 = (RP)[(K0) + 1],                 \
                    R2 = (RP)[(K0) + 2], R3 = (RP)[(K0) + 3];                 \
        const ushort4 V0 = *(const ushort4*)(yb + (size_t)(R0.x & 0xFFFFu) * ROW_ELEMS + l4); \
        const ushort4 V1 = *(const ushort4*)(yb + (size_t)(R1.x & 0xFFFFu) * ROW_ELEMS + l4); \
        const ushort4 V2 = *(const ushort4*)(yb + (size_t)(R2.x & 0xFFFFu) * ROW_ELEMS + l4); \
        const ushort4 V3 = *(const ushort4*)(yb + (size_t)(R3.x & 0xFFFFu) * ROW_ELEMS + l4); \
        float w;                                                              \
        w = dec_w(R0, t);                                                     \
        acc.x += bf16_to_f32(V0.x) * w; acc.y += bf16_to_f32(V0.y) * w;       \
        acc.z += bf16_to_f32(V0.z) * w; acc.w += bf16_to_f32(V0.w) * w;       \
        w = dec_w(R1, t);                                                     \
        acc.x += bf16_to_f32(V1.x) * w; acc.y += bf16_to_f32(V1.y) * w;       \
        acc.z += bf16_to_f32(V1.z) * w; acc.w += bf16_to_f32(V1.w) * w;       \
        w = dec_w(R2, t);                                                     \
        acc.x += bf16_to_f32(V2.x) * w; acc.y += bf16_to_f32(V2.y) * w;       \
        acc.z += bf16_to_f32(V2.z) * w; acc.w += bf16_to_f32(V2.w) * w;       \
        w = dec_w(R3, t);                                                     \
        acc.x += bf16_to_f32(V3.x) * w; acc.y += bf16_to_f32(V3.y) * w;       \
        acc.z += bf16_to_f32(V3.z) * w; acc.w += bf16_to_f32(V3.w) * w;       \
    }

// ---------------------------------------------------------------------------
// K3: accumulate (R8 structure). One 64-lane wave per node, 4 nodes/block.
// Dense contiguous 8B CSR rows at bktF[r]/8B + nodeinfo offsets.
// Fused ovf fixup (expected ~100 entries).
// ---------------------------------------------------------------------------
__global__ __launch_bounds__(256) void accumulate_kernel(
    const unsigned short* __restrict__ yb, const int4* __restrict__ bktF,
    const unsigned int* __restrict__ nodeinfo,
    const int4* __restrict__ ovf, const int* __restrict__ ovf_cnt,
    const float* __restrict__ b, float* __restrict__ out)
{
    const int lane = threadIdx.x & 63;
    const int n    = blockIdx.x * 4 + (threadIdx.x >> 6);
    const int t    = lane >> 4;
    const int l4   = lane * 4;

    const unsigned info = nodeinfo[n];
    const int r = n >> 6;
    const uint2* rp = (const uint2*)(bktF + (size_t)r * CAPF) + (info & 0xFFFFu);
    const int d = (int)(info >> 16);

    float4 acc = make_float4(0.f, 0.f, 0.f, 0.f);

    int k = 0;
    for (; k + 8 <= d; k += 8) { BATCH4(rp, k); BATCH4(rp, k + 4); }
    if (k + 4 <= d) { BATCH4(rp, k); k += 4; }
    for (; k < d; ++k) {
        const uint2 rr = rp[k];
        const float w = dec_w(rr, t);
        const ushort4 v = *(const ushort4*)(yb + (size_t)(rr.x & 0xFFFFu) * ROW_ELEMS + l4);
        acc.x += bf16_to_f32(v.x) * w;
        acc.y += bf16_to_f32(v.y) * w;
        acc.z += bf16_to_f32(v.z) * w;
        acc.w += bf16_to_f32(v.w) * w;
    }

    // ---- fused overflow fixup (expected ~100 entries) ----
    {
        int m = *ovf_cnt;
        if (m > OVF_CAP) m = OVF_CAP;
        for (int i = 0; i < m; ++i) {
            const int4 rr = ovf[i];
            if (rr.z == n) {
                const uint2 r2 = make_uint2((unsigned)rr.x, (unsigned)rr.y);
                const float w = dec_w(r2, t);
                const ushort4 v = *(const ushort4*)(yb + (size_t)(r2.x & 0xFFFFu) * ROW_ELEMS + l4);
                acc.x += bf16_to_f32(v.x) * w;
                acc.y += bf16_to_f32(v.y) * w;
                acc.z += bf16_to_f32(v.z) * w;
                acc.w += bf16_to_f32(v.w) * w;
            }
        }
    }

    const float4 bv = *(const float4*)(b + (lane & 15) * 4);
    acc.x += bv.x; acc.y += bv.y; acc.z += bv.z; acc.w += bv.w;
    *(float4*)(out + (size_t)n * ROW_ELEMS + l4) = acc;
}

extern "C" void kernel_launch(void* const* d_in, const int* in_sizes, int n_in,
                              void* d_out, int out_size, void* d_ws, size_t ws_size,
                              hipStream_t stream) {
    const float* x   = (const float*)d_in[0];  // (N,T,64)
    const float* ew  = (const float*)d_in[1];  // (T,E)
    const int*   src = (const int*)  d_in[2];  // (E,)
    const int*   dst = (const int*)  d_in[3];  // (E,)
    const float* W   = (const float*)d_in[4];  // (64,64)
    const float* b   = (const float*)d_in[5];  // (64,)
    float*       out = (float*)d_out;          // (N,T,64)

    char* ws = (char*)d_ws;
    size_t off = 0;
    auto alloc = [&](size_t bytes) {
        void* p = ws + off;
        off += (bytes + 255) & ~(size_t)255;
        return p;
    };
    unsigned short* yb       = (unsigned short*)alloc((size_t)ROWS * 64 * 2);        // 10.24 MB
    int*            gcnt     = (int*)  alloc((NRANGE + 1) * sizeof(int));            // 1.3 KB
    int4*           ovf      = (int4*) alloc((size_t)OVF_CAP * sizeof(int4));        // 64 KB
    unsigned int*   nodeinfo = (unsigned int*)alloc((size_t)NRANGE * RB * 4);        // 80 KB
    int4*           bktF     = (int4*) alloc((size_t)NRANGE * CAPF * sizeof(int4));  // 15.4 MB
    int*            ovf_cnt  = gcnt + NRANGE;
    (void)ws_size;   // total ~25.8 MB

    hipError_t err = hipMemsetAsync(gcnt, 0, (NRANGE + 1) * sizeof(int), stream);
    (void)err;
    build_kernel<<<PART_BLOCKS + TRANSFORM_BLOCKS, 256, 0, stream>>>(
        x, W, yb, src, dst, ew, gcnt, bktF, ovf, ovf_cnt);
    sort_kernel<<<NRANGE, 256, 0, stream>>>(gcnt, bktF, nodeinfo);
    accumulate_kernel<<<N_NODES / 4, 256, 0, stream>>>(
        yb, bktF, nodeinfo, ovf, ovf_cnt, b, out);
}

// Round 10
// 169.170 us; speedup vs baseline: 1.2015x; 1.2015x over previous
//
#include <hip/hip_runtime.h>

// Problem constants: N=20000, T=4, F_IN=F_OUT=64, E=640000
#define N_NODES 20000
#define T_STEPS 4
#define F_DIM   64
#define E_EDGES 640000
#define ROWS    (N_NODES * T_STEPS)   // 80000
#define ROW_ELEMS (T_STEPS * F_DIM)   // 256 elems per node row

#define RB       64                   // dst nodes per range
#define NRANGE   313                  // ceil(20000/64)
#define CAPF     3072                 // records per range (lambda ~2048, +22 sigma)
#define PART_BLOCKS   128
#define EPB      5000                 // edges per partition block
#define TRANSFORM_BLOCKS (ROWS / 64)  // 1250
#define OVF_CAP  4096

__device__ __forceinline__ unsigned short f32_to_bf16_rne(float f) {
    unsigned u = __float_as_uint(f);
    u += 0x7FFFu + ((u >> 16) & 1u);
    return (unsigned short)(u >> 16);
}
__device__ __forceinline__ float bf16_to_f32(unsigned short h) {
    return __uint_as_float((unsigned)h << 16);
}
// 10-bit fixed-point weight in [0,1): abs err <= 2^-11 = 4.9e-4 — negligible
// vs the bf16-y contribution to absmax (0.125). Frees 6 bits for d6.
__device__ __forceinline__ unsigned w_to_u10(float f) {
    unsigned q = __float2uint_rn(f * 1024.0f);
    return q > 1023u ? 1023u : q;
}

// Record layout (8B, self-contained):
//  lo = src[0:16) | w0[16:26) | w1.lo6[26:32)
//  hi = w1.hi4[0:4) | w2[4:14) | w3[14:24) | d6[24:30)
__device__ __forceinline__ float dec_w(uint2 r, int t) {
    const unsigned q = t == 0 ? (r.x >> 16) & 1023u
                     : t == 1 ? (((r.x >> 26) & 63u) | ((r.y & 15u) << 6))
                     : t == 2 ? (r.y >> 4) & 1023u
                     :          (r.y >> 14) & 1023u;
    return (float)q * (1.0f / 1024.0f);
}

// ---------------------------------------------------------------------------
// R9 post-mortem: full-line flush VALIDATED on bytes (WRITE 32.4->23.1MB,
// bkt written ~1.25x useful) but the schedule was serial (250/256 lanes,
// 40 barriers/block, 313-bucket scan per round, occ 10%) -> 79us. R10 keeps
// the mechanism, fixes the schedule: two-pass LDS range-sort per 5000-edge
// block; ONE scan, ~6 barriers total; flush is i-major so consecutive
// threads hit consecutive global addresses within ~16-record range runs
// (mostly full 64B lines); one atomicAdd per (block,range) = 40k total.
//  blocks [0,128):      partition (two-pass LDS sort + coalesced flush)
//  blocks [128,1378):   transform — y = x @ W^T (64x64 fp32) stored bf16.
// ---------------------------------------------------------------------------
__global__ __launch_bounds__(256) void build_kernel(
    const float* __restrict__ x, const float* __restrict__ W,
    unsigned short* __restrict__ yb,
    const int* __restrict__ src, const int* __restrict__ dst,
    const float* __restrict__ ew,
    int* __restrict__ gcnt, uint2* __restrict__ bkt,
    int4* __restrict__ ovf, int* __restrict__ ovf_cnt)
{
    __shared__ uint2 rec8[EPB];          // 40 KB (transform overlays wt here)
    __shared__ int off[NRANGE + 1];
    __shared__ int cur[NRANGE];
    __shared__ int gb[NRANGE];
    __shared__ int s[256];

    const int tid = threadIdx.x;

    if (blockIdx.x < PART_BLOCKS) {
        int* hcnt = gb;                  // reuse gb as the histogram
        for (int i = tid; i < NRANGE; i += 256) hcnt[i] = 0;
        __syncthreads();
        const int base = blockIdx.x * EPB;

        // pass 1: range histogram (LDS atomics)
        for (int j = 0; j < 20; ++j) {
            const int idx = j * 256 + tid;
            if (idx < EPB) atomicAdd(&hcnt[dst[base + idx] >> 6], 1);
        }
        __syncthreads();

        // scan: thread t owns bins 2t, 2t+1; Hillis-Steele over 256 partials
        int c0 = 0, c1 = 0;
        if (2 * tid < NRANGE)     c0 = hcnt[2 * tid];
        if (2 * tid + 1 < NRANGE) c1 = hcnt[2 * tid + 1];
        const int p = c0 + c1;
        s[tid] = p;
        __syncthreads();
        for (int o = 1; o < 256; o <<= 1) {
            const int v = (tid >= o) ? s[tid - o] : 0;
            __syncthreads();
            s[tid] += v;
            __syncthreads();
        }
        const int excl = s[tid] - p;
        if (2 * tid < NRANGE) { off[2 * tid] = excl; cur[2 * tid] = excl; }
        if (2 * tid + 1 <= NRANGE) {
            off[2 * tid + 1] = excl + c0;
            if (2 * tid + 1 < NRANGE) cur[2 * tid + 1] = excl + c0;
        }
        __syncthreads();

        // pass 2: re-read edges (L2-hot), pack 8B record, LDS scatter by range
        for (int j = 0; j < 20; ++j) {
            const int idx = j * 256 + tid;
            if (idx < EPB) {
                const int e = base + idx;
                const unsigned w0 = w_to_u10(ew[e]);
                const unsigned w1 = w_to_u10(ew[E_EDGES + e]);
                const unsigned w2 = w_to_u10(ew[2 * E_EDGES + e]);
                const unsigned w3 = w_to_u10(ew[3 * E_EDGES + e]);
                const unsigned ss = (unsigned)src[e];
                const int d = dst[e];
                const unsigned lo = ss | (w0 << 16) | ((w1 & 63u) << 26);
                const unsigned hi = (w1 >> 6) | (w2 << 4) | (w3 << 14) |
                                    ((unsigned)(d & 63) << 24);
                const int r = d >> 6;
                const int pth = atomicAdd(&cur[r], 1);
                rec8[pth] = make_uint2(lo, hi);
            }
        }
        __syncthreads();

        // global base per range (one atomic per (block,range))
        for (int r = tid; r < NRANGE; r += 256)
            gb[r] = atomicAdd(&gcnt[r], cur[r] - off[r]);
        __syncthreads();

        // flush: i-major -> coalesced runs of full lines
        for (int i = tid; i < EPB; i += 256) {
            int lo_ = 0, hi_ = NRANGE;
            while (hi_ - lo_ > 1) {
                const int mid = (lo_ + hi_) >> 1;
                if (off[mid] <= i) lo_ = mid; else hi_ = mid;
            }
            const int r = lo_;
            const int slot = gb[r] + (i - off[r]);
            const uint2 rc = rec8[i];
            if (slot < CAPF) {
                bkt[(size_t)r * CAPF + slot] = rc;
            } else {
                const int o = atomicAdd(ovf_cnt, 1);
                if (o < OVF_CAP) {
                    int4 q; q.x = (int)rc.x; q.y = (int)rc.y;
                    q.z = r * RB + (int)((rc.y >> 24) & 63u); q.w = 0;
                    ovf[o] = q;
                }
            }
        }
        return;
    }

    // ---- transform: y = x @ W^T (64x64 fp32) stored bf16 ----
    float* wt = (float*)rec8;            // 16KB overlay
    const int row0 = (blockIdx.x - PART_BLOCKS) * 64;

    {
        const int o  = tid & 63;
        const int fb = (tid >> 6) * 16;
#pragma unroll
        for (int k = 0; k < 16; ++k) {
            const int f = fb + k;
            wt[f * 64 + o] = W[o * 64 + f];
        }
    }
    __syncthreads();

    const int rg = tid >> 4;
    const int oq = (tid & 15) * 4;

    float acc[4][4];
#pragma unroll
    for (int i = 0; i < 4; ++i)
#pragma unroll
        for (int j = 0; j < 4; ++j) acc[i][j] = 0.0f;

    const float4* xg4 = (const float4*)(x + (size_t)(row0 + rg * 4) * 64);

#pragma unroll 4
    for (int fc = 0; fc < 16; ++fc) {
        float4 xv[4];
#pragma unroll
        for (int i = 0; i < 4; ++i) xv[i] = xg4[i * 16 + fc];
#pragma unroll
        for (int j = 0; j < 4; ++j) {
            const int f = fc * 4 + j;
            const float4 w4 = *(const float4*)&wt[f * 64 + oq];
            const float xj0 = j == 0 ? xv[0].x : j == 1 ? xv[0].y : j == 2 ? xv[0].z : xv[0].w;
            const float xj1 = j == 0 ? xv[1].x : j == 1 ? xv[1].y : j == 2 ? xv[1].z : xv[1].w;
            const float xj2 = j == 0 ? xv[2].x : j == 1 ? xv[2].y : j == 2 ? xv[2].z : xv[2].w;
            const float xj3 = j == 0 ? xv[3].x : j == 1 ? xv[3].y : j == 2 ? xv[3].z : xv[3].w;
            acc[0][0] += xj0 * w4.x; acc[0][1] += xj0 * w4.y; acc[0][2] += xj0 * w4.z; acc[0][3] += xj0 * w4.w;
            acc[1][0] += xj1 * w4.x; acc[1][1] += xj1 * w4.y; acc[1][2] += xj1 * w4.z; acc[1][3] += xj1 * w4.w;
            acc[2][0] += xj2 * w4.x; acc[2][1] += xj2 * w4.y; acc[2][2] += xj2 * w4.z; acc[2][3] += xj2 * w4.w;
            acc[3][0] += xj3 * w4.x; acc[3][1] += xj3 * w4.y; acc[3][2] += xj3 * w4.z; acc[3][3] += xj3 * w4.w;
        }
    }

#pragma unroll
    for (int i = 0; i < 4; ++i) {
        const int r = row0 + rg * 4 + i;
        ushort4 h;
        h.x = f32_to_bf16_rne(acc[i][0]);
        h.y = f32_to_bf16_rne(acc[i][1]);
        h.z = f32_to_bf16_rne(acc[i][2]);
        h.w = f32_to_bf16_rne(acc[i][3]);
        *(ushort4*)(yb + (size_t)r * 64 + oq) = h;
    }
}

// ---------------------------------------------------------------------------
// K2: per-range LDS sort -> dense per-node CSR, in place (all reads into LDS
// before first write; only block r touches row r). nodeinfo[n]=off|deg<<16.
// ---------------------------------------------------------------------------
__global__ __launch_bounds__(256) void sort_kernel(
    const int* __restrict__ gcnt, uint2* __restrict__ bkt,
    unsigned int* __restrict__ nodeinfo)
{
    __shared__ uint2 lrec[CAPF];         // 24 KB
    __shared__ int h2[RB], ps[RB], c2[RB];
    const int tid = threadIdx.x;
    const int r   = blockIdx.x;

    int m = gcnt[r]; if (m > CAPF) m = CAPF;
    uint2* rowp = bkt + (size_t)r * CAPF;

    for (int i = tid; i < m; i += 256) lrec[i] = rowp[i];
    if (tid < RB) { h2[tid] = 0; c2[tid] = 0; }
    __syncthreads();

    for (int i = tid; i < m; i += 256) atomicAdd(&h2[(lrec[i].y >> 24) & 63u], 1);
    __syncthreads();

    if (tid == 0) {
        int run = 0;
        for (int i = 0; i < RB; ++i) { ps[i] = run; run += h2[i]; }
    }
    __syncthreads();

    if (tid < RB)
        nodeinfo[r * RB + tid] = (unsigned)ps[tid] | ((unsigned)h2[tid] << 16);

    for (int i = tid; i < m; i += 256) {
        const uint2 rc = lrec[i];
        const int d6 = (rc.y >> 24) & 63;
        const int rk = atomicAdd(&c2[d6], 1);
        rowp[ps[d6] + rk] = rc;
    }
}

// 4-record batch: all register indices compile-time (rule #20).
#define BATCH4(RP, K0)                                                        \
    {                                                                         \
        const uint2 R0 = (RP)[(K0) + 0], R1 = (RP)[(K0) + 1],                 \
                    R2 = (RP)[(K0) + 2], R3 = (RP)[(K0) + 3];                 \
        const ushort4 V0 = *(const ushort4*)(yb + (size_t)(R0.x & 0xFFFFu) * ROW_ELEMS + l4); \
        const ushort4 V1 = *(const ushort4*)(yb + (size_t)(R1.x & 0xFFFFu) * ROW_ELEMS + l4); \
        const ushort4 V2 = *(const ushort4*)(yb + (size_t)(R2.x & 0xFFFFu) * ROW_ELEMS + l4); \
        const ushort4 V3 = *(const ushort4*)(yb + (size_t)(R3.x & 0xFFFFu) * ROW_ELEMS + l4); \
        float w;                                                              \
        w = dec_w(R0, t);                                                     \
        acc.x += bf16_to_f32(V0.x) * w; acc.y += bf16_to_f32(V0.y) * w;       \
        acc.z += bf16_to_f32(V0.z) * w; acc.w += bf16_to_f32(V0.w) * w;       \
        w = dec_w(R1, t);                                                     \
        acc.x += bf16_to_f32(V1.x) * w; acc.y += bf16_to_f32(V1.y) * w;       \
        acc.z += bf16_to_f32(V1.z) * w; acc.w += bf16_to_f32(V1.w) * w;       \
        w = dec_w(R2, t);                                                     \
        acc.x += bf16_to_f32(V2.x) * w; acc.y += bf16_to_f32(V2.y) * w;       \
        acc.z += bf16_to_f32(V2.z) * w; acc.w += bf16_to_f32(V2.w) * w;       \
        w = dec_w(R3, t);                                                     \
        acc.x += bf16_to_f32(V3.x) * w; acc.y += bf16_to_f32(V3.y) * w;       \
        acc.z += bf16_to_f32(V3.z) * w; acc.w += bf16_to_f32(V3.w) * w;       \
    }

// ---------------------------------------------------------------------------
// K3: accumulate (proven <50us). One 64-lane wave per node, 4 nodes/block.
// Dense contiguous 8B CSR rows; fused ovf fixup (expected ~0 entries).
// ---------------------------------------------------------------------------
__global__ __launch_bounds__(256) void accumulate_kernel(
    const unsigned short* __restrict__ yb, const uint2* __restrict__ bkt,
    const unsigned int* __restrict__ nodeinfo,
    const int4* __restrict__ ovf, const int* __restrict__ ovf_cnt,
    const float* __restrict__ b, float* __restrict__ out)
{
    const int lane = threadIdx.x & 63;
    const int n    = blockIdx.x * 4 + (threadIdx.x >> 6);
    const int t    = lane >> 4;
    const int l4   = lane * 4;

    const unsigned info = nodeinfo[n];
    const int r = n >> 6;
    const uint2* rp = bkt + (size_t)r * CAPF + (info & 0xFFFFu);
    const int d = (int)(info >> 16);

    float4 acc = make_float4(0.f, 0.f, 0.f, 0.f);

    int k = 0;
    for (; k + 8 <= d; k += 8) { BATCH4(rp, k); BATCH4(rp, k + 4); }
    if (k + 4 <= d) { BATCH4(rp, k); k += 4; }
    for (; k < d; ++k) {
        const uint2 rr = rp[k];
        const float w = dec_w(rr, t);
        const ushort4 v = *(const ushort4*)(yb + (size_t)(rr.x & 0xFFFFu) * ROW_ELEMS + l4);
        acc.x += bf16_to_f32(v.x) * w;
        acc.y += bf16_to_f32(v.y) * w;
        acc.z += bf16_to_f32(v.z) * w;
        acc.w += bf16_to_f32(v.w) * w;
    }

    // ---- fused overflow fixup (expected empty) ----
    {
        int m = *ovf_cnt;
        if (m > OVF_CAP) m = OVF_CAP;
        for (int i = 0; i < m; ++i) {
            const int4 rr = ovf[i];
            if (rr.z == n) {
                const uint2 r2 = make_uint2((unsigned)rr.x, (unsigned)rr.y);
                const float w = dec_w(r2, t);
                const ushort4 v = *(const ushort4*)(yb + (size_t)(r2.x & 0xFFFFu) * ROW_ELEMS + l4);
                acc.x += bf16_to_f32(v.x) * w;
                acc.y += bf16_to_f32(v.y) * w;
                acc.z += bf16_to_f32(v.z) * w;
                acc.w += bf16_to_f32(v.w) * w;
            }
        }
    }

    const float4 bv = *(const float4*)(b + (lane & 15) * 4);
    acc.x += bv.x; acc.y += bv.y; acc.z += bv.z; acc.w += bv.w;
    *(float4*)(out + (size_t)n * ROW_ELEMS + l4) = acc;
}

extern "C" void kernel_launch(void* const* d_in, const int* in_sizes, int n_in,
                              void* d_out, int out_size, void* d_ws, size_t ws_size,
                              hipStream_t stream) {
    const float* x   = (const float*)d_in[0];  // (N,T,64)
    const float* ew  = (const float*)d_in[1];  // (T,E)
    const int*   src = (const int*)  d_in[2];  // (E,)
    const int*   dst = (const int*)  d_in[3];  // (E,)
    const float* W   = (const float*)d_in[4];  // (64,64)
    const float* b   = (const float*)d_in[5];  // (64,)
    float*       out = (float*)d_out;          // (N,T,64)

    char* ws = (char*)d_ws;
    size_t off = 0;
    auto alloc = [&](size_t bytes) {
        void* p = ws + off;
        off += (bytes + 255) & ~(size_t)255;
        return p;
    };
    unsigned short* yb       = (unsigned short*)alloc((size_t)ROWS * 64 * 2);        // 10.24 MB
    int*            gcnt     = (int*)  alloc((NRANGE + 1) * sizeof(int));            // 1.3 KB
    int4*           ovf      = (int4*) alloc((size_t)OVF_CAP * sizeof(int4));        // 64 KB
    unsigned int*   nodeinfo = (unsigned int*)alloc((size_t)NRANGE * RB * 4);        // 80 KB
    uint2*          bkt      = (uint2*)alloc((size_t)NRANGE * CAPF * sizeof(uint2)); // 7.69 MB
    int*            ovf_cnt  = gcnt + NRANGE;
    (void)ws_size;   // total ~18 MB

    hipError_t err = hipMemsetAsync(gcnt, 0, (NRANGE + 1) * sizeof(int), stream);
    (void)err;
    build_kernel<<<PART_BLOCKS + TRANSFORM_BLOCKS, 256, 0, stream>>>(
        x, W, yb, src, dst, ew, gcnt, bkt, ovf, ovf_cnt);
    sort_kernel<<<NRANGE, 256, 0, stream>>>(gcnt, bkt, nodeinfo);
    accumulate_kernel<<<N_NODES / 4, 256, 0, stream>>>(
        yb, bkt, nodeinfo, ovf, ovf_cnt, b, out);
}

// Round 11
// 156.448 us; speedup vs baseline: 1.2992x; 1.0813x over previous
//
#include <hip/hip_runtime.h>

// Problem constants: N=20000, T=4, F_IN=F_OUT=64, E=640000
#define N_NODES 20000
#define T_STEPS 4
#define F_DIM   64
#define E_EDGES 640000
#define ROWS    (N_NODES * T_STEPS)   // 80000
#define ROW_ELEMS (T_STEPS * F_DIM)   // 256 elems per node row

#define RB       64                   // dst nodes per range
#define NRANGE   313                  // ceil(20000/64)
#define CAPF     3072                 // records per range (lambda ~2048, +22 sigma)
#define PART_BLOCKS   256
#define EPB      2500                 // edges per partition block
#define TRANSFORM_BLOCKS (ROWS / 64)  // 1250
#define OVF_CAP  4096

__device__ __forceinline__ unsigned short f32_to_bf16_rne(float f) {
    unsigned u = __float_as_uint(f);
    u += 0x7FFFu + ((u >> 16) & 1u);
    return (unsigned short)(u >> 16);
}
__device__ __forceinline__ float bf16_to_f32(unsigned short h) {
    return __uint_as_float((unsigned)h << 16);
}
// 10-bit fixed-point weight in [0,1): abs err <= 2^-11 = 4.9e-4 — negligible
// vs the bf16-y contribution to absmax (0.125). Frees 6 bits for d6.
__device__ __forceinline__ unsigned w_to_u10(float f) {
    unsigned q = __float2uint_rn(f * 1024.0f);
    return q > 1023u ? 1023u : q;
}

// Record layout (8B, self-contained):
//  lo = src[0:16) | w0[16:26) | w1.lo6[26:32)
//  hi = w1.hi4[0:4) | w2[4:14) | w3[14:24) | d6[24:30)
__device__ __forceinline__ float dec_w(uint2 r, int t) {
    const unsigned q = t == 0 ? (r.x >> 16) & 1023u
                     : t == 1 ? (((r.x >> 26) & 63u) | ((r.y & 15u) << 6))
                     : t == 2 ? (r.y >> 4) & 1023u
                     :          (r.y >> 14) & 1023u;
    return (float)q * (1.0f / 1024.0f);
}

// ---------------------------------------------------------------------------
// R10 post-mortem: bytes SOLVED (WRITE 16MB, bkt ~1.1x useful) but build
// still 46us at 750GB/s, 13% occupancy: only 128 partition blocks (half the
// CUs idle post-transform) and a 9-deep dependent-LDS binary search per
// flushed record (187K bank conflicts). R11: (1) 256 blocks x 2500 edges —
// full CU coverage, half the per-block serial path (accepting ~2x write amp
// on bkt, +5MB); (2) rid[] ushort array records each record's range at LDS-
// scatter time — flush does ONE independent LDS read instead of the search.
//  blocks [0,256):      partition (two-pass LDS sort + coalesced flush)
//  blocks [256,1506):   transform — y = x @ W^T (64x64 fp32) stored bf16.
// ---------------------------------------------------------------------------
__global__ __launch_bounds__(256) void build_kernel(
    const float* __restrict__ x, const float* __restrict__ W,
    unsigned short* __restrict__ yb,
    const int* __restrict__ src, const int* __restrict__ dst,
    const float* __restrict__ ew,
    int* __restrict__ gcnt, uint2* __restrict__ bkt,
    int4* __restrict__ ovf, int* __restrict__ ovf_cnt)
{
    __shared__ uint2 rec8[EPB];              // 20 KB (transform overlays wt)
    __shared__ unsigned short rid[EPB];      // 5 KB: range id per staged record
    __shared__ int off[NRANGE + 1];
    __shared__ int cur[NRANGE];
    __shared__ int gb[NRANGE];
    __shared__ int s[256];

    const int tid = threadIdx.x;

    if (blockIdx.x < PART_BLOCKS) {
        int* hcnt = gb;                      // reuse gb as the histogram
        for (int i = tid; i < NRANGE; i += 256) hcnt[i] = 0;
        __syncthreads();
        const int base = blockIdx.x * EPB;

        // pass 1: range histogram (LDS atomics)
        for (int j = 0; j < 10; ++j) {
            const int idx = j * 256 + tid;
            if (idx < EPB) atomicAdd(&hcnt[dst[base + idx] >> 6], 1);
        }
        __syncthreads();

        // scan: thread t owns bins 2t, 2t+1; Hillis-Steele over 256 partials
        int c0 = 0, c1 = 0;
        if (2 * tid < NRANGE)     c0 = hcnt[2 * tid];
        if (2 * tid + 1 < NRANGE) c1 = hcnt[2 * tid + 1];
        const int p = c0 + c1;
        s[tid] = p;
        __syncthreads();
        for (int o = 1; o < 256; o <<= 1) {
            const int v = (tid >= o) ? s[tid - o] : 0;
            __syncthreads();
            s[tid] += v;
            __syncthreads();
        }
        const int excl = s[tid] - p;
        if (2 * tid < NRANGE) { off[2 * tid] = excl; cur[2 * tid] = excl; }
        if (2 * tid + 1 <= NRANGE) {
            off[2 * tid + 1] = excl + c0;
            if (2 * tid + 1 < NRANGE) cur[2 * tid + 1] = excl + c0;
        }
        __syncthreads();

        // pass 2: re-read edges (L2-hot), pack 8B record, LDS scatter by range
        for (int j = 0; j < 10; ++j) {
            const int idx = j * 256 + tid;
            if (idx < EPB) {
                const int e = base + idx;
                const unsigned w0 = w_to_u10(ew[e]);
                const unsigned w1 = w_to_u10(ew[E_EDGES + e]);
                const unsigned w2 = w_to_u10(ew[2 * E_EDGES + e]);
                const unsigned w3 = w_to_u10(ew[3 * E_EDGES + e]);
                const unsigned ss = (unsigned)src[e];
                const int d = dst[e];
                const unsigned lo = ss | (w0 << 16) | ((w1 & 63u) << 26);
                const unsigned hi = (w1 >> 6) | (w2 << 4) | (w3 << 14) |
                                    ((unsigned)(d & 63) << 24);
                const int r = d >> 6;
                const int pth = atomicAdd(&cur[r], 1);
                rec8[pth] = make_uint2(lo, hi);
                rid[pth]  = (unsigned short)r;
            }
        }
        __syncthreads();

        // global base per range (one atomic per (block,range))
        for (int r = tid; r < NRANGE; r += 256)
            gb[r] = atomicAdd(&gcnt[r], cur[r] - off[r]);
        __syncthreads();

        // flush: i-major -> coalesced runs; range id from rid (no search)
        for (int i = tid; i < EPB; i += 256) {
            const int r = (int)rid[i];
            const int slot = gb[r] + (i - off[r]);
            const uint2 rc = rec8[i];
            if (slot < CAPF) {
                bkt[(size_t)r * CAPF + slot] = rc;
            } else {
                const int o = atomicAdd(ovf_cnt, 1);
                if (o < OVF_CAP) {
                    int4 q; q.x = (int)rc.x; q.y = (int)rc.y;
                    q.z = r * RB + (int)((rc.y >> 24) & 63u); q.w = 0;
                    ovf[o] = q;
                }
            }
        }
        return;
    }

    // ---- transform: y = x @ W^T (64x64 fp32) stored bf16 ----
    float* wt = (float*)rec8;            // 16KB overlay
    const int row0 = (blockIdx.x - PART_BLOCKS) * 64;

    {
        const int o  = tid & 63;
        const int fb = (tid >> 6) * 16;
#pragma unroll
        for (int k = 0; k < 16; ++k) {
            const int f = fb + k;
            wt[f * 64 + o] = W[o * 64 + f];
        }
    }
    __syncthreads();

    const int rg = tid >> 4;
    const int oq = (tid & 15) * 4;

    float acc[4][4];
#pragma unroll
    for (int i = 0; i < 4; ++i)
#pragma unroll
        for (int j = 0; j < 4; ++j) acc[i][j] = 0.0f;

    const float4* xg4 = (const float4*)(x + (size_t)(row0 + rg * 4) * 64);

#pragma unroll 4
    for (int fc = 0; fc < 16; ++fc) {
        float4 xv[4];
#pragma unroll
        for (int i = 0; i < 4; ++i) xv[i] = xg4[i * 16 + fc];
#pragma unroll
        for (int j = 0; j < 4; ++j) {
            const int f = fc * 4 + j;
            const float4 w4 = *(const float4*)&wt[f * 64 + oq];
            const float xj0 = j == 0 ? xv[0].x : j == 1 ? xv[0].y : j == 2 ? xv[0].z : xv[0].w;
            const float xj1 = j == 0 ? xv[1].x : j == 1 ? xv[1].y : j == 2 ? xv[1].z : xv[1].w;
            const float xj2 = j == 0 ? xv[2].x : j == 1 ? xv[2].y : j == 2 ? xv[2].z : xv[2].w;
            const float xj3 = j == 0 ? xv[3].x : j == 1 ? xv[3].y : j == 2 ? xv[3].z : xv[3].w;
            acc[0][0] += xj0 * w4.x; acc[0][1] += xj0 * w4.y; acc[0][2] += xj0 * w4.z; acc[0][3] += xj0 * w4.w;
            acc[1][0] += xj1 * w4.x; acc[1][1] += xj1 * w4.y; acc[1][2] += xj1 * w4.z; acc[1][3] += xj1 * w4.w;
            acc[2][0] += xj2 * w4.x; acc[2][1] += xj2 * w4.y; acc[2][2] += xj2 * w4.z; acc[2][3] += xj2 * w4.w;
            acc[3][0] += xj3 * w4.x; acc[3][1] += xj3 * w4.y; acc[3][2] += xj3 * w4.z; acc[3][3] += xj3 * w4.w;
        }
    }

#pragma unroll
    for (int i = 0; i < 4; ++i) {
        const int r = row0 + rg * 4 + i;
        ushort4 h;
        h.x = f32_to_bf16_rne(acc[i][0]);
        h.y = f32_to_bf16_rne(acc[i][1]);
        h.z = f32_to_bf16_rne(acc[i][2]);
        h.w = f32_to_bf16_rne(acc[i][3]);
        *(ushort4*)(yb + (size_t)r * 64 + oq) = h;
    }
}

// ---------------------------------------------------------------------------
// K2: per-range LDS sort -> dense per-node CSR, in place (all reads into LDS
// before first write; only block r touches row r). nodeinfo[n]=off|deg<<16.
// ---------------------------------------------------------------------------
__global__ __launch_bounds__(256) void sort_kernel(
    const int* __restrict__ gcnt, uint2* __restrict__ bkt,
    unsigned int* __restrict__ nodeinfo)
{
    __shared__ uint2 lrec[CAPF];         // 24 KB
    __shared__ int h2[RB], ps[RB], c2[RB];
    const int tid = threadIdx.x;
    const int r   = blockIdx.x;

    int m = gcnt[r]; if (m > CAPF) m = CAPF;
    uint2* rowp = bkt + (size_t)r * CAPF;

    for (int i = tid; i < m; i += 256) lrec[i] = rowp[i];
    if (tid < RB) { h2[tid] = 0; c2[tid] = 0; }
    __syncthreads();

    for (int i = tid; i < m; i += 256) atomicAdd(&h2[(lrec[i].y >> 24) & 63u], 1);
    __syncthreads();

    if (tid == 0) {
        int run = 0;
        for (int i = 0; i < RB; ++i) { ps[i] = run; run += h2[i]; }
    }
    __syncthreads();

    if (tid < RB)
        nodeinfo[r * RB + tid] = (unsigned)ps[tid] | ((unsigned)h2[tid] << 16);

    for (int i = tid; i < m; i += 256) {
        const uint2 rc = lrec[i];
        const int d6 = (rc.y >> 24) & 63;
        const int rk = atomicAdd(&c2[d6], 1);
        rowp[ps[d6] + rk] = rc;
    }
}

// 4-record batch: all register indices compile-time (rule #20).
#define BATCH4(RP, K0)                                                        \
    {                                                                         \
        const uint2 R0 = (RP)[(K0) + 0], R1 = (RP)[(K0) + 1],                 \
                    R2 = (RP)[(K0) + 2], R3 = (RP)[(K0) + 3];                 \
        const ushort4 V0 = *(const ushort4*)(yb + (size_t)(R0.x & 0xFFFFu) * ROW_ELEMS + l4); \
        const ushort4 V1 = *(const ushort4*)(yb + (size_t)(R1.x & 0xFFFFu) * ROW_ELEMS + l4); \
        const ushort4 V2 = *(const ushort4*)(yb + (size_t)(R2.x & 0xFFFFu) * ROW_ELEMS + l4); \
        const ushort4 V3 = *(const ushort4*)(yb + (size_t)(R3.x & 0xFFFFu) * ROW_ELEMS + l4); \
        float w;                                                              \
        w = dec_w(R0, t);                                                     \
        acc.x += bf16_to_f32(V0.x) * w; acc.y += bf16_to_f32(V0.y) * w;       \
        acc.z += bf16_to_f32(V0.z) * w; acc.w += bf16_to_f32(V0.w) * w;       \
        w = dec_w(R1, t);                                                     \
        acc.x += bf16_to_f32(V1.x) * w; acc.y += bf16_to_f32(V1.y) * w;       \
        acc.z += bf16_to_f32(V1.z) * w; acc.w += bf16_to_f32(V1.w) * w;       \
        w = dec_w(R2, t);                                                     \
        acc.x += bf16_to_f32(V2.x) * w; acc.y += bf16_to_f32(V2.y) * w;       \
        acc.z += bf16_to_f32(V2.z) * w; acc.w += bf16_to_f32(V2.w) * w;       \
        w = dec_w(R3, t);                                                     \
        acc.x += bf16_to_f32(V3.x) * w; acc.y += bf16_to_f32(V3.y) * w;       \
        acc.z += bf16_to_f32(V3.z) * w; acc.w += bf16_to_f32(V3.w) * w;       \
    }

// ---------------------------------------------------------------------------
// K3: accumulate (proven). One 64-lane wave per node, 4 nodes/block.
// Dense contiguous 8B CSR rows; fused ovf fixup (expected ~0 entries).
// ---------------------------------------------------------------------------
__global__ __launch_bounds__(256) void accumulate_kernel(
    const unsigned short* __restrict__ yb, const uint2* __restrict__ bkt,
    const unsigned int* __restrict__ nodeinfo,
    const int4* __restrict__ ovf, const int* __restrict__ ovf_cnt,
    const float* __restrict__ b, float* __restrict__ out)
{
    const int lane = threadIdx.x & 63;
    const int n    = blockIdx.x * 4 + (threadIdx.x >> 6);
    const int t    = lane >> 4;
    const int l4   = lane * 4;

    const unsigned info = nodeinfo[n];
    const int r = n >> 6;
    const uint2* rp = bkt + (size_t)r * CAPF + (info & 0xFFFFu);
    const int d = (int)(info >> 16);

    float4 acc = make_float4(0.f, 0.f, 0.f, 0.f);

    int k = 0;
    for (; k + 8 <= d; k += 8) { BATCH4(rp, k); BATCH4(rp, k + 4); }
    if (k + 4 <= d) { BATCH4(rp, k); k += 4; }
    for (; k < d; ++k) {
        const uint2 rr = rp[k];
        const float w = dec_w(rr, t);
        const ushort4 v = *(const ushort4*)(yb + (size_t)(rr.x & 0xFFFFu) * ROW_ELEMS + l4);
        acc.x += bf16_to_f32(v.x) * w;
        acc.y += bf16_to_f32(v.y) * w;
        acc.z += bf16_to_f32(v.z) * w;
        acc.w += bf16_to_f32(v.w) * w;
    }

    // ---- fused overflow fixup (expected empty) ----
    {
        int m = *ovf_cnt;
        if (m > OVF_CAP) m = OVF_CAP;
        for (int i = 0; i < m; ++i) {
            const int4 rr = ovf[i];
            if (rr.z == n) {
                const uint2 r2 = make_uint2((unsigned)rr.x, (unsigned)rr.y);
                const float w = dec_w(r2, t);
                const ushort4 v = *(const ushort4*)(yb + (size_t)(r2.x & 0xFFFFu) * ROW_ELEMS + l4);
                acc.x += bf16_to_f32(v.x) * w;
                acc.y += bf16_to_f32(v.y) * w;
                acc.z += bf16_to_f32(v.z) * w;
                acc.w += bf16_to_f32(v.w) * w;
            }
        }
    }

    const float4 bv = *(const float4*)(b + (lane & 15) * 4);
    acc.x += bv.x; acc.y += bv.y; acc.z += bv.z; acc.w += bv.w;
    *(float4*)(out + (size_t)n * ROW_ELEMS + l4) = acc;
}

extern "C" void kernel_launch(void* const* d_in, const int* in_sizes, int n_in,
                              void* d_out, int out_size, void* d_ws, size_t ws_size,
                              hipStream_t stream) {
    const float* x   = (const float*)d_in[0];  // (N,T,64)
    const float* ew  = (const float*)d_in[1];  // (T,E)
    const int*   src = (const int*)  d_in[2];  // (E,)
    const int*   dst = (const int*)  d_in[3];  // (E,)
    const float* W   = (const float*)d_in[4];  // (64,64)
    const float* b   = (const float*)d_in[5];  // (64,)
    float*       out = (float*)d_out;          // (N,T,64)

    char* ws = (char*)d_ws;
    size_t off = 0;
    auto alloc = [&](size_t bytes) {
        void* p = ws + off;
        off += (bytes + 255) & ~(size_t)255;
        return p;
    };
    unsigned short* yb       = (unsigned short*)alloc((size_t)ROWS * 64 * 2);        // 10.24 MB
    int*            gcnt     = (int*)  alloc((NRANGE + 1) * sizeof(int));            // 1.3 KB
    int4*           ovf      = (int4*) alloc((size_t)OVF_CAP * sizeof(int4));        // 64 KB
    unsigned int*   nodeinfo = (unsigned int*)alloc((size_t)NRANGE * RB * 4);        // 80 KB
    uint2*          bkt      = (uint2*)alloc((size_t)NRANGE * CAPF * sizeof(uint2)); // 7.69 MB
    int*            ovf_cnt  = gcnt + NRANGE;
    (void)ws_size;   // total ~18 MB

    hipError_t err = hipMemsetAsync(gcnt, 0, (NRANGE + 1) * sizeof(int), stream);
    (void)err;
    build_kernel<<<PART_BLOCKS + TRANSFORM_BLOCKS, 256, 0, stream>>>(
        x, W, yb, src, dst, ew, gcnt, bkt, ovf, ovf_cnt);
    sort_kernel<<<NRANGE, 256, 0, stream>>>(gcnt, bkt, nodeinfo);
    accumulate_kernel<<<N_NODES / 4, 256, 0, stream>>>(
        yb, bkt, nodeinfo, ovf, ovf_cnt, b, out);
}

// Round 12
// 154.057 us; speedup vs baseline: 1.3193x; 1.0155x over previous
//
#include <hip/hip_runtime.h>

// Problem constants: N=20000, T=4, F_IN=F_OUT=64, E=640000
#define N_NODES 20000
#define T_STEPS 4
#define F_DIM   64
#define E_EDGES 640000
#define ROWS    (N_NODES * T_STEPS)   // 80000
#define ROW_ELEMS (T_STEPS * F_DIM)   // 256 elems per node row

#define RB       64                   // dst nodes per range
#define NRANGE   313                  // ceil(20000/64)
#define CAPF     3072                 // records per range (lambda ~2048, +22 sigma)
#define PART_BLOCKS   256
#define EPB      2500                 // edges per partition block
#define TRANSFORM_BLOCKS (ROWS / 128) // 625 (512-thread blocks, 128 rows each)
#define OVF_CAP  4096

__device__ __forceinline__ unsigned short f32_to_bf16_rne(float f) {
    unsigned u = __float_as_uint(f);
    u += 0x7FFFu + ((u >> 16) & 1u);
    return (unsigned short)(u >> 16);
}
__device__ __forceinline__ float bf16_to_f32(unsigned short h) {
    return __uint_as_float((unsigned)h << 16);
}
// 10-bit fixed-point weight in [0,1): abs err <= 2^-11 = 4.9e-4 — negligible
// vs the bf16-y contribution to absmax (0.125). Frees 6 bits for d6.
__device__ __forceinline__ unsigned w_to_u10(float f) {
    unsigned q = __float2uint_rn(f * 1024.0f);
    return q > 1023u ? 1023u : q;
}

// Record layout (8B, self-contained):
//  lo = src[0:16) | w0[16:26) | w1.lo6[26:32)
//  hi = w1.hi4[0:4) | w2[4:14) | w3[14:24) | d6[24:30)
__device__ __forceinline__ float dec_w(uint2 r, int t) {
    const unsigned q = t == 0 ? (r.x >> 16) & 1023u
                     : t == 1 ? (((r.x >> 26) & 63u) | ((r.y & 15u) << 6))
                     : t == 2 ? (r.y >> 4) & 1023u
                     :          (r.y >> 14) & 1023u;
    return (float)q * (1.0f / 1024.0f);
}

// ---------------------------------------------------------------------------
// R11 post-mortem: 156us; all our kernels below the 44us fill (harness
// workspace poison, untouchable). Build's tail (R10 counters: 750GB/s, 13%
// occ) ran 4 waves/CU with a 2-pass global read. R12, one change: 512-thread
// partition blocks, SINGLE-PASS — each thread loads its ~5 edges once into
// registers (hist runs off regs; load latency issued up-front, overlaps the
// scan), 8 waves/CU in the tail, one-bin-per-thread scan. Transform becomes
// 128 rows per 512-thread block. Sort/accumulate untouched.
//  blocks [0,256):      partition (reg-load + LDS sort + coalesced flush)
//  blocks [256,881):    transform — y = x @ W^T (64x64 fp32) stored bf16.
// ---------------------------------------------------------------------------
__global__ __launch_bounds__(512) void build_kernel(
    const float* __restrict__ x, const float* __restrict__ W,
    unsigned short* __restrict__ yb,
    const int* __restrict__ src, const int* __restrict__ dst,
    const float* __restrict__ ew,
    int* __restrict__ gcnt, uint2* __restrict__ bkt,
    int4* __restrict__ ovf, int* __restrict__ ovf_cnt)
{
    __shared__ uint2 rec8[EPB];              // 20 KB (transform overlays wt)
    __shared__ unsigned short rid[EPB];      // 5 KB: range id per staged record
    __shared__ int off[NRANGE];
    __shared__ int cur[NRANGE];
    __shared__ int gb[NRANGE];
    __shared__ int s[512];

    const int tid = threadIdx.x;

    if (blockIdx.x < PART_BLOCKS) {
        int* hcnt = gb;                      // reuse gb as the histogram
        for (int i = tid; i < NRANGE; i += 512) hcnt[i] = 0;
        __syncthreads();
        const int base = blockIdx.x * EPB;

        // single pass: load all inputs to registers, pack, histogram.
        unsigned lo5[5], hi5[5];
        int r5[5];
#pragma unroll
        for (int j = 0; j < 5; ++j) {
            const int idx = j * 512 + tid;
            r5[j] = -1;
            if (idx < EPB) {
                const int e = base + idx;
                const unsigned w0 = w_to_u10(ew[e]);
                const unsigned w1 = w_to_u10(ew[E_EDGES + e]);
                const unsigned w2 = w_to_u10(ew[2 * E_EDGES + e]);
                const unsigned w3 = w_to_u10(ew[3 * E_EDGES + e]);
                const unsigned ss = (unsigned)src[e];
                const int d = dst[e];
                lo5[j] = ss | (w0 << 16) | ((w1 & 63u) << 26);
                hi5[j] = (w1 >> 6) | (w2 << 4) | (w3 << 14) |
                         ((unsigned)(d & 63) << 24);
                r5[j] = d >> 6;
                atomicAdd(&hcnt[r5[j]], 1);
            }
        }
        __syncthreads();

        // scan: one bin per thread (NRANGE=313 < 512), Hillis-Steele
        const int p = (tid < NRANGE) ? hcnt[tid] : 0;
        s[tid] = p;
        __syncthreads();
        for (int o = 1; o < 512; o <<= 1) {
            const int v = (tid >= o) ? s[tid - o] : 0;
            __syncthreads();
            s[tid] += v;
            __syncthreads();
        }
        if (tid < NRANGE) {
            const int excl = s[tid] - p;
            off[tid] = excl;
            cur[tid] = excl;
        }
        __syncthreads();

        // LDS scatter by range (records already packed in registers)
#pragma unroll
        for (int j = 0; j < 5; ++j) {
            if (r5[j] >= 0) {
                const int pth = atomicAdd(&cur[r5[j]], 1);
                rec8[pth] = make_uint2(lo5[j], hi5[j]);
                rid[pth]  = (unsigned short)r5[j];
            }
        }
        __syncthreads();

        // global base per range (one atomic per (block,range))
        if (tid < NRANGE)
            gb[tid] = atomicAdd(&gcnt[tid], cur[tid] - off[tid]);
        __syncthreads();

        // flush: i-major -> coalesced runs; range id from rid (no search)
        for (int i = tid; i < EPB; i += 512) {
            const int r = (int)rid[i];
            const int slot = gb[r] + (i - off[r]);
            const uint2 rc = rec8[i];
            if (slot < CAPF) {
                bkt[(size_t)r * CAPF + slot] = rc;
            } else {
                const int o = atomicAdd(ovf_cnt, 1);
                if (o < OVF_CAP) {
                    int4 q; q.x = (int)rc.x; q.y = (int)rc.y;
                    q.z = r * RB + (int)((rc.y >> 24) & 63u); q.w = 0;
                    ovf[o] = q;
                }
            }
        }
        return;
    }

    // ---- transform: y = x @ W^T (64x64 fp32), 128 rows per 512-thr block ----
    float* wt = (float*)rec8;            // 16KB overlay
    const int row0 = (blockIdx.x - PART_BLOCKS) * 128;

    {
        const int o  = tid & 63;
        const int fb = (tid >> 6) * 8;   // 8 groups x 8 f-values
#pragma unroll
        for (int k = 0; k < 8; ++k) {
            const int f = fb + k;
            wt[f * 64 + o] = W[o * 64 + f];
        }
    }
    __syncthreads();

    const int rg = tid >> 4;             // 0..31: row group (4 rows)
    const int oq = (tid & 15) * 4;

    float acc[4][4];
#pragma unroll
    for (int i = 0; i < 4; ++i)
#pragma unroll
        for (int j = 0; j < 4; ++j) acc[i][j] = 0.0f;

    const float4* xg4 = (const float4*)(x + (size_t)(row0 + rg * 4) * 64);

#pragma unroll 4
    for (int fc = 0; fc < 16; ++fc) {
        float4 xv[4];
#pragma unroll
        for (int i = 0; i < 4; ++i) xv[i] = xg4[i * 16 + fc];
#pragma unroll
        for (int j = 0; j < 4; ++j) {
            const int f = fc * 4 + j;
            const float4 w4 = *(const float4*)&wt[f * 64 + oq];
            const float xj0 = j == 0 ? xv[0].x : j == 1 ? xv[0].y : j == 2 ? xv[0].z : xv[0].w;
            const float xj1 = j == 0 ? xv[1].x : j == 1 ? xv[1].y : j == 2 ? xv[1].z : xv[1].w;
            const float xj2 = j == 0 ? xv[2].x : j == 1 ? xv[2].y : j == 2 ? xv[2].z : xv[2].w;
            const float xj3 = j == 0 ? xv[3].x : j == 1 ? xv[3].y : j == 2 ? xv[3].z : xv[3].w;
            acc[0][0] += xj0 * w4.x; acc[0][1] += xj0 * w4.y; acc[0][2] += xj0 * w4.z; acc[0][3] += xj0 * w4.w;
            acc[1][0] += xj1 * w4.x; acc[1][1] += xj1 * w4.y; acc[1][2] += xj1 * w4.z; acc[1][3] += xj1 * w4.w;
            acc[2][0] += xj2 * w4.x; acc[2][1] += xj2 * w4.y; acc[2][2] += xj2 * w4.z; acc[2][3] += xj2 * w4.w;
            acc[3][0] += xj3 * w4.x; acc[3][1] += xj3 * w4.y; acc[3][2] += xj3 * w4.z; acc[3][3] += xj3 * w4.w;
        }
    }

#pragma unroll
    for (int i = 0; i < 4; ++i) {
        const int r = row0 + rg * 4 + i;
        ushort4 h;
        h.x = f32_to_bf16_rne(acc[i][0]);
        h.y = f32_to_bf16_rne(acc[i][1]);
        h.z = f32_to_bf16_rne(acc[i][2]);
        h.w = f32_to_bf16_rne(acc[i][3]);
        *(ushort4*)(yb + (size_t)r * 64 + oq) = h;
    }
}

// ---------------------------------------------------------------------------
// K2: per-range LDS sort -> dense per-node CSR, in place (all reads into LDS
// before first write; only block r touches row r). nodeinfo[n]=off|deg<<16.
// ---------------------------------------------------------------------------
__global__ __launch_bounds__(256) void sort_kernel(
    const int* __restrict__ gcnt, uint2* __restrict__ bkt,
    unsigned int* __restrict__ nodeinfo)
{
    __shared__ uint2 lrec[CAPF];         // 24 KB
    __shared__ int h2[RB], ps[RB], c2[RB];
    const int tid = threadIdx.x;
    const int r   = blockIdx.x;

    int m = gcnt[r]; if (m > CAPF) m = CAPF;
    uint2* rowp = bkt + (size_t)r * CAPF;

    for (int i = tid; i < m; i += 256) lrec[i] = rowp[i];
    if (tid < RB) { h2[tid] = 0; c2[tid] = 0; }
    __syncthreads();

    for (int i = tid; i < m; i += 256) atomicAdd(&h2[(lrec[i].y >> 24) & 63u], 1);
    __syncthreads();

    if (tid == 0) {
        int run = 0;
        for (int i = 0; i < RB; ++i) { ps[i] = run; run += h2[i]; }
    }
    __syncthreads();

    if (tid < RB)
        nodeinfo[r * RB + tid] = (unsigned)ps[tid] | ((unsigned)h2[tid] << 16);

    for (int i = tid; i < m; i += 256) {
        const uint2 rc = lrec[i];
        const int d6 = (rc.y >> 24) & 63;
        const int rk = atomicAdd(&c2[d6], 1);
        rowp[ps[d6] + rk] = rc;
    }
}

// 4-record batch: all register indices compile-time (rule #20).
#define BATCH4(RP, K0)                                                        \
    {                                                                         \
        const uint2 R0 = (RP)[(K0) + 0], R1 = (RP)[(K0) + 1],                 \
                    R2 = (RP)[(K0) + 2], R3 = (RP)[(K0) + 3];                 \
        const ushort4 V0 = *(const ushort4*)(yb + (size_t)(R0.x & 0xFFFFu) * ROW_ELEMS + l4); \
        const ushort4 V1 = *(const ushort4*)(yb + (size_t)(R1.x & 0xFFFFu) * ROW_ELEMS + l4); \
        const ushort4 V2 = *(const ushort4*)(yb + (size_t)(R2.x & 0xFFFFu) * ROW_ELEMS + l4); \
        const ushort4 V3 = *(const ushort4*)(yb + (size_t)(R3.x & 0xFFFFu) * ROW_ELEMS + l4); \
        float w;                                                              \
        w = dec_w(R0, t);                                                     \
        acc.x += bf16_to_f32(V0.x) * w; acc.y += bf16_to_f32(V0.y) * w;       \
        acc.z += bf16_to_f32(V0.z) * w; acc.w += bf16_to_f32(V0.w) * w;       \
        w = dec_w(R1, t);                                                     \
        acc.x += bf16_to_f32(V1.x) * w; acc.y += bf16_to_f32(V1.y) * w;       \
        acc.z += bf16_to_f32(V1.z) * w; acc.w += bf16_to_f32(V1.w) * w;       \
        w = dec_w(R2, t);                                                     \
        acc.x += bf16_to_f32(V2.x) * w; acc.y += bf16_to_f32(V2.y) * w;       \
        acc.z += bf16_to_f32(V2.z) * w; acc.w += bf16_to_f32(V2.w) * w;       \
        w = dec_w(R3, t);                                                     \
        acc.x += bf16_to_f32(V3.x) * w; acc.y += bf16_to_f32(V3.y) * w;       \
        acc.z += bf16_to_f32(V3.z) * w; acc.w += bf16_to_f32(V3.w) * w;       \
    }

// ---------------------------------------------------------------------------
// K3: accumulate (proven). One 64-lane wave per node, 4 nodes/block.
// Dense contiguous 8B CSR rows; fused ovf fixup (expected ~0 entries).
// ---------------------------------------------------------------------------
__global__ __launch_bounds__(256) void accumulate_kernel(
    const unsigned short* __restrict__ yb, const uint2* __restrict__ bkt,
    const unsigned int* __restrict__ nodeinfo,
    const int4* __restrict__ ovf, const int* __restrict__ ovf_cnt,
    const float* __restrict__ b, float* __restrict__ out)
{
    const int lane = threadIdx.x & 63;
    const int n    = blockIdx.x * 4 + (threadIdx.x >> 6);
    const int t    = lane >> 4;
    const int l4   = lane * 4;

    const unsigned info = nodeinfo[n];
    const int r = n >> 6;
    const uint2* rp = bkt + (size_t)r * CAPF + (info & 0xFFFFu);
    const int d = (int)(info >> 16);

    float4 acc = make_float4(0.f, 0.f, 0.f, 0.f);

    int k = 0;
    for (; k + 8 <= d; k += 8) { BATCH4(rp, k); BATCH4(rp, k + 4); }
    if (k + 4 <= d) { BATCH4(rp, k); k += 4; }
    for (; k < d; ++k) {
        const uint2 rr = rp[k];
        const float w = dec_w(rr, t);
        const ushort4 v = *(const ushort4*)(yb + (size_t)(rr.x & 0xFFFFu) * ROW_ELEMS + l4);
        acc.x += bf16_to_f32(v.x) * w;
        acc.y += bf16_to_f32(v.y) * w;
        acc.z += bf16_to_f32(v.z) * w;
        acc.w += bf16_to_f32(v.w) * w;
    }

    // ---- fused overflow fixup (expected empty) ----
    {
        int m = *ovf_cnt;
        if (m > OVF_CAP) m = OVF_CAP;
        for (int i = 0; i < m; ++i) {
            const int4 rr = ovf[i];
            if (rr.z == n) {
                const uint2 r2 = make_uint2((unsigned)rr.x, (unsigned)rr.y);
                const float w = dec_w(r2, t);
                const ushort4 v = *(const ushort4*)(yb + (size_t)(r2.x & 0xFFFFu) * ROW_ELEMS + l4);
                acc.x += bf16_to_f32(v.x) * w;
                acc.y += bf16_to_f32(v.y) * w;
                acc.z += bf16_to_f32(v.z) * w;
                acc.w += bf16_to_f32(v.w) * w;
            }
        }
    }

    const float4 bv = *(const float4*)(b + (lane & 15) * 4);
    acc.x += bv.x; acc.y += bv.y; acc.z += bv.z; acc.w += bv.w;
    *(float4*)(out + (size_t)n * ROW_ELEMS + l4) = acc;
}

extern "C" void kernel_launch(void* const* d_in, const int* in_sizes, int n_in,
                              void* d_out, int out_size, void* d_ws, size_t ws_size,
                              hipStream_t stream) {
    const float* x   = (const float*)d_in[0];  // (N,T,64)
    const float* ew  = (const float*)d_in[1];  // (T,E)
    const int*   src = (const int*)  d_in[2];  // (E,)
    const int*   dst = (const int*)  d_in[3];  // (E,)
    const float* W   = (const float*)d_in[4];  // (64,64)
    const float* b   = (const float*)d_in[5];  // (64,)
    float*       out = (float*)d_out;          // (N,T,64)

    char* ws = (char*)d_ws;
    size_t off = 0;
    auto alloc = [&](size_t bytes) {
        void* p = ws + off;
        off += (bytes + 255) & ~(size_t)255;
        return p;
    };
    unsigned short* yb       = (unsigned short*)alloc((size_t)ROWS * 64 * 2);        // 10.24 MB
    int*            gcnt     = (int*)  alloc((NRANGE + 1) * sizeof(int));            // 1.3 KB
    int4*           ovf      = (int4*) alloc((size_t)OVF_CAP * sizeof(int4));        // 64 KB
    unsigned int*   nodeinfo = (unsigned int*)alloc((size_t)NRANGE * RB * 4);        // 80 KB
    uint2*          bkt      = (uint2*)alloc((size_t)NRANGE * CAPF * sizeof(uint2)); // 7.69 MB
    int*            ovf_cnt  = gcnt + NRANGE;
    (void)ws_size;   // total ~18 MB

    hipError_t err = hipMemsetAsync(gcnt, 0, (NRANGE + 1) * sizeof(int), stream);
    (void)err;
    build_kernel<<<PART_BLOCKS + TRANSFORM_BLOCKS, 512, 0, stream>>>(
        x, W, yb, src, dst, ew, gcnt, bkt, ovf, ovf_cnt);
    sort_kernel<<<NRANGE, 256, 0, stream>>>(gcnt, bkt, nodeinfo);
    accumulate_kernel<<<N_NODES / 4, 256, 0, stream>>>(
        yb, bkt, nodeinfo, ovf, ovf_cnt, b, out);
}